// Round 3
// baseline (7777.986 us; speedup 1.0000x reference)
//
#include <hip/hip_runtime.h>
#include <math.h>

#define LOG2E 1.4426950408889634f
#define LN2   0.6931471805599453f
#define LGA  -5.545177444479562f   // -ln 256
#define LGG  -6.238324625039508f   // -ln 512

typedef short    short8  __attribute__((ext_vector_type(8)));
typedef float    floatx4 __attribute__((ext_vector_type(4)));
typedef _Float16 half8   __attribute__((ext_vector_type(8)));

__constant__ int c_pi[28] = {0,0,0,0,0,0,0,1,1,1,1,1,1,2,2,2,2,2,3,3,3,3,4,4,4,5,5,6};
__constant__ int c_pj[28] = {1,2,3,4,5,6,7,2,3,4,5,6,7,3,4,5,6,7,4,5,6,7,5,6,7,6,7,7};

// ---------------- static device storage ----------------
__device__ unsigned short g_cellsL[16*256*256];   // bf16 bits, gathered local cells
__device__ unsigned short g_cellsG[8*512*256];    // bf16 bits, gathered global cells
__device__ float g_x2L[16*256];
__device__ float g_x2G[8*512];
__device__ int   g_idxL[16*256];
__device__ int   g_idxG[8*512];
// fp16 cost matrices. Local: [0,56)=Cxy, [56,112)=Cyx(T), [112,128)=Cxx. 16.8 MB
__device__ _Float16 g_CL[128*256*256];
// Global: [0,28)=Cxy, [28,56)=Cyx(T), [56,64)=Cxx. 33.6 MB
__device__ _Float16 g_CG[64*512*512];
__device__ float g_fL[2][56*256];
__device__ float g_gL[2][56*256];
__device__ float g_pxL[2][16*256];
__device__ float g_fG[2][28*512];
__device__ float g_gG[2][28*512];
__device__ float g_pxG[2][8*512];
__device__ unsigned g_ctr[108];                   // per-group barrier counters

// ---------------- helpers ----------------
__device__ __forceinline__ unsigned short f2bf(float f) {
    unsigned u = __float_as_uint(f);
    u += 0x7fffu + ((u >> 16) & 1u);          // RNE; inputs are finite
    return (unsigned short)(u >> 16);
}

// ---------------- index lists: first-m matches in order (ballot scan) -------
__global__ void k_index(const int* __restrict__ labels, const int* __restrict__ subg) {
    int b = blockIdx.x, lane = threadIdx.x;   // 24 blocks x 64 threads
    int want_l, want_s, cap; int* out;
    if (b < 16) { want_l = b >> 3; want_s = b & 7; cap = 256; out = g_idxL + b*256; }
    else        { want_l = -1;     want_s = b - 16; cap = 512; out = g_idxG + (b-16)*512; }
    int cnt = 0;
    for (int base = 0; base < 4096; base += 64) {
        int i = base + lane;
        bool m = (subg[i] == want_s) && (want_l < 0 || labels[i] == want_l);
        unsigned long long mask = __ballot(m);
        int pos = cnt + __popcll(mask & ((1ull << lane) - 1ull));
        if (m && pos < cap) out[pos] = i;
        cnt += __popcll(mask);
    }
}

// ---------------- gather rows -> bf16 cells + fp32 sq-norms -----------------
__global__ void k_gather(const float* __restrict__ feat) {
    int wv = blockIdx.x*4 + (threadIdx.x >> 6);   // 8192 waves, one row each
    int lane = threadIdx.x & 63;
    const float* src; unsigned short* dst; float* x2out;
    if (wv < 4096) {
        int c = wv >> 8, row = wv & 255;
        src = feat + (size_t)g_idxL[c*256+row]*256;
        dst = g_cellsL + (size_t)(c*256+row)*256;
        x2out = g_x2L + c*256 + row;
    } else {
        int v = wv - 4096; int c = v >> 9, row = v & 511;
        src = feat + (size_t)g_idxG[c*512+row]*256;
        dst = g_cellsG + (size_t)(c*512+row)*256;
        x2out = g_x2G + c*512 + row;
    }
    floatx4 v4 = *(const floatx4*)(src + lane*4);
    float s = v4[0]*v4[0] + v4[1]*v4[1] + v4[2]*v4[2] + v4[3]*v4[3];
    unsigned lo = (unsigned)f2bf(v4[0]) | ((unsigned)f2bf(v4[1]) << 16);
    unsigned hi = (unsigned)f2bf(v4[2]) | ((unsigned)f2bf(v4[3]) << 16);
    unsigned* d32 = (unsigned*)dst;
    d32[lane*2] = lo; d32[lane*2+1] = hi;
    for (int o = 32; o; o >>= 1) s += __shfl_xor(s, o);
    if (lane == 0) *x2out = s;
}

// ---------------- cost matrices via bf16 MFMA, 64x64 tile per block ---------
// C_ij = 0.5*max(x2_i + y2_j - 2*x.y, 0), stored fp16.
// B-panel staged in LDS in kk-panel layout (conflict-free b128 reads);
// A-strip (16 rows x 256) held in registers per wave.
__global__ __launch_bounds__(256) void k_gemm() {
    __shared__ _Float16 sB[16384];            // 32 KB
    int b = blockIdx.x, tid = threadIdx.x, lane = tid & 63, w = tid >> 6;
    const unsigned short *A, *B; _Float16* Cout; const float *x2a, *x2b;
    int m, tI, tJ;
    if (b < 2048) {                            // local: 128 matrices x 16 tiles
        int mm = b >> 4, t = b & 15; tI = t >> 2; tJ = t & 3; m = 256;
        int ca, cb;
        if (mm < 56)       { int lbl = mm/28,  q = mm%28;  ca = lbl*8 + c_pi[q]; cb = lbl*8 + c_pj[q]; }
        else if (mm < 112) { int p = mm-56; int lbl = p/28, q = p%28;
                             ca = lbl*8 + c_pj[q]; cb = lbl*8 + c_pi[q]; }
        else               { int c = mm-112; ca = cb = c; }
        A = g_cellsL + (size_t)ca*65536; B = g_cellsL + (size_t)cb*65536;
        x2a = g_x2L + ca*256; x2b = g_x2L + cb*256;
        Cout = g_CL + (size_t)mm*65536;
    } else {                                   // global: 64 matrices x 64 tiles
        int v = b - 2048; int mm = v >> 6, t = v & 63; tI = t >> 3; tJ = t & 7; m = 512;
        int ca, cb;
        if (mm < 28)      { ca = c_pi[mm];    cb = c_pj[mm]; }
        else if (mm < 56) { ca = c_pj[mm-28]; cb = c_pi[mm-28]; }
        else              { ca = cb = mm-56; }
        A = g_cellsG + (size_t)ca*131072; B = g_cellsG + (size_t)cb*131072;
        x2a = g_x2G + ca*512; x2b = g_x2G + cb*512;
        Cout = g_CG + (size_t)mm*262144;
    }
    // stage B rows [tJ*64, +64): element (j, kk*32+q*8+e) -> sB[((kk*64+j)*4+q)*8+e]
    const unsigned short* Bp0 = B + (size_t)(tJ*64)*256;
    for (int i = tid; i < 2048; i += 256) {
        int j = i >> 5, c8 = i & 31, kk = c8 >> 2, q = c8 & 3;
        *(short8*)(sB + (size_t)((kk*64 + j)*4 + q)*8) = *(const short8*)(Bp0 + j*256 + c8*8);
    }
    int r = lane & 15, quad = lane >> 4;
    const unsigned short* Ap = A + (size_t)(tI*64 + w*16 + r)*256 + quad*8;
    short8 a[8];
    #pragma unroll
    for (int kk = 0; kk < 8; kk++) a[kk] = *(const short8*)(Ap + kk*32);
    __syncthreads();
    #pragma unroll
    for (int tj = 0; tj < 4; tj++) {
        floatx4 acc = {0.f, 0.f, 0.f, 0.f};
        #pragma unroll
        for (int kk = 0; kk < 8; kk++) {
            short8 bv = *(const short8*)(sB + (size_t)((kk*64 + tj*16 + r)*4 + quad)*8);
            acc = __builtin_amdgcn_mfma_f32_16x16x32_bf16(a[kk], bv, acc, 0, 0, 0);
        }
        int jc = tJ*64 + tj*16 + r;
        float y2 = x2b[jc];
        #pragma unroll
        for (int rr = 0; rr < 4; rr++) {
            int ir = tI*64 + w*16 + quad*4 + rr;
            float v = x2a[ir] + y2 - 2.f*acc[rr];
            Cout[(size_t)ir*m + jc] = (_Float16)(0.5f*fmaxf(v, 0.f));
        }
    }
}

// ---------------- zero parity-0 potentials + barrier counters ---------------
__global__ void k_init() {
    int t = blockIdx.x*256 + threadIdx.x;   // 65536 threads
    if (t < 108) g_ctr[t] = 0;
    if      (t < 14336) g_fL[0][t] = 0.f;
    else if (t < 28672) g_gL[0][t-14336] = 0.f;
    else if (t < 32768) g_pxL[0][t-28672] = 0.f;
    else if (t < 47104) g_fG[0][t-32768] = 0.f;
    else if (t < 61440) g_gG[0][t-47104] = 0.f;
    else                g_pxG[0][t-61440] = 0.f;
}

// ---------------- persistent Sinkhorn unit runner ---------------------------
// Block owns a row-slice of one matrix (M=256: 128 rows, M=512: 64 rows);
// first LR rows parked in LDS, rest streamed from cache. Runs all 122
// averaged iterations + 1 extrapolation internally; cross-block exchange of
// potentials via agent-scope atomics + per-group counter barrier.
template<int M>
__device__ void run_unit(const _Float16* __restrict__ Cmat, _Float16* sC,
                         int rb, float* fv0, float* fv1,
                         const float* hv0, const float* hv1,
                         unsigned* ctr, int gsize, float loga)
{
    const int LR = (M == 256) ? 80 : 40;    // rows resident in LDS (40 KB)
    const int W0 = (M == 256) ? 16 : 32;    // shfl butterfly start
    int tid = threadIdx.x, lane = tid & 63, w = tid >> 6;
    int co = (M == 256) ? (lane & 31) : lane;
    int rsel = (M == 256) ? (lane >> 5) : 0;

    // park rows [rb, rb+LR) in LDS (contiguous 40 KB copy)
    {
        const short8* src8 = (const short8*)(Cmat + (size_t)rb*M);
        short8* dst8 = (short8*)sC;
        for (int i = tid; i < 2560; i += 256) dst8[i] = src8[i];
    }
    __syncthreads();

    float fprev[16];
    #pragma unroll
    for (int s = 0; s < 16; s++) fprev[s] = 0.f;   // parity-0 carry = zeros

    double e = 1024.0;                      // eps schedule, ratio 0.81, clip 1e-8
    unsigned tgt = 0;
    for (int k = 0; k < 123; k++) {
        bool fin = (k == 122);              // final extrapolation pass
        double ed = (e < 1e-8) ? 1e-8 : e;
        e *= 0.81;
        float eps = (float)ed;
        float inv_eps = (float)(1.0/ed);
        int po = fin ? 0 : (k & 1);
        bool hard = (eps < 1e-5f);          // |err| <= eps*ln(M): negligible
        const float* hs = po ? hv1 : hv0;
        float* fn = po ? fv0 : fv1;

        float h[8];
        #pragma unroll
        for (int q = 0; q < 8; q++) {
            float hq = __hip_atomic_load((float*)&hs[co*8 + q],
                                         __ATOMIC_RELAXED, __HIP_MEMORY_SCOPE_AGENT);
            h[q] = loga + hq*inv_eps;
        }
        #pragma unroll
        for (int s = 0; s < 16; s++) {
            int row = (M == 256) ? (w*32 + s*2 + rsel) : (w*16 + s);
            half8 cv;
            if (row < LR) cv = *(const half8*)(sC + (size_t)row*M + co*8);
            else          cv = *(const half8*)(Cmat + (size_t)(rb + row)*M + co*8);
            float tv[8]; float mx = -3.4e38f;
            #pragma unroll
            for (int q = 0; q < 8; q++) {
                float t = fmaf(-(float)cv[q], inv_eps, h[q]);
                tv[q] = t; mx = fmaxf(mx, t);
            }
            #pragma unroll
            for (int o = W0; o; o >>= 1) mx = fmaxf(mx, __shfl_xor(mx, o));
            float ft;
            if (!hard) {
                float sum = 0.f;
                #pragma unroll
                for (int q = 0; q < 8; q++) sum += exp2f((tv[q] - mx)*LOG2E);
                #pragma unroll
                for (int o = W0; o; o >>= 1) sum += __shfl_xor(sum, o);
                ft = -eps*(mx + LN2*__log2f(sum));
            } else {
                ft = -eps*mx;
            }
            float fnew = fin ? ft : 0.5f*(fprev[s] + ft);
            fprev[s] = fnew;
            if (co == 0)
                __hip_atomic_store(&fn[rb + row], fnew,
                                   __ATOMIC_RELAXED, __HIP_MEMORY_SCOPE_AGENT);
        }
        if (!fin) {                         // group barrier (Jacobi exchange)
            tgt += (unsigned)gsize;
            __syncthreads();                // drains vmem: stores visible pre-barrier
            if (tid == 0) {
                __hip_atomic_fetch_add(ctr, 1u, __ATOMIC_RELEASE, __HIP_MEMORY_SCOPE_AGENT);
                while (__hip_atomic_load(ctr, __ATOMIC_ACQUIRE, __HIP_MEMORY_SCOPE_AGENT) < tgt)
                    __builtin_amdgcn_s_sleep(1);
            }
            __syncthreads();
        }
    }
}

// 768 blocks: [0,224) gpair-f | [224,448) gpair-g | [448,512) gcell |
//             [512,624) lpair-f | [624,736) lpair-g | [736,768) lcell
__global__ __launch_bounds__(256, 3) void k_sink() {
    __shared__ _Float16 sC[20480];          // 40 KB slab
    int b = blockIdx.x;
    if (b < 512) {                          // global units, M=512, 64 rows/block
        const _Float16* Cm; float *f0, *f1; const float *h0, *h1;
        unsigned* ct; int gs, rb;
        if (b < 448) {
            int side = (b >= 224); int v = side ? b - 224 : b;
            int p = v >> 3, j = v & 7; rb = j*64;
            Cm = g_CG + (size_t)(side ? 28 + p : p)*262144;
            if (!side) { h0 = g_gG[0]+p*512; h1 = g_gG[1]+p*512; f0 = g_fG[0]+p*512; f1 = g_fG[1]+p*512; }
            else       { h0 = g_fG[0]+p*512; h1 = g_fG[1]+p*512; f0 = g_gG[0]+p*512; f1 = g_gG[1]+p*512; }
            ct = g_ctr + p; gs = 16;
        } else {
            int v = b - 448; int c = v >> 3, j = v & 7; rb = j*64;
            Cm = g_CG + (size_t)(56 + c)*262144;
            h0 = g_pxG[0]+c*512; h1 = g_pxG[1]+c*512; f0 = g_pxG[0]+c*512; f1 = g_pxG[1]+c*512;
            ct = g_ctr + 28 + c; gs = 8;
        }
        run_unit<512>(Cm, sC, rb, f0, f1, h0, h1, ct, gs, LGG);
    } else {                                // local units, M=256, 128 rows/block
        const _Float16* Cm; float *f0, *f1; const float *h0, *h1;
        unsigned* ct; int gs, rb;
        int v = b - 512;
        if (v < 224) {
            int side = (v >= 112); int u = side ? v - 112 : v;
            int p = u >> 1, j = u & 1; rb = j*128;
            Cm = g_CL + (size_t)(side ? 56 + p : p)*65536;
            if (!side) { h0 = g_gL[0]+p*256; h1 = g_gL[1]+p*256; f0 = g_fL[0]+p*256; f1 = g_fL[1]+p*256; }
            else       { h0 = g_fL[0]+p*256; h1 = g_fL[1]+p*256; f0 = g_gL[0]+p*256; f1 = g_gL[1]+p*256; }
            ct = g_ctr + 36 + p; gs = 4;
        } else {
            int u = v - 224; int c = u >> 1, j = u & 1; rb = j*128;
            Cm = g_CL + (size_t)(112 + c)*65536;
            h0 = g_pxL[0]+c*256; h1 = g_pxL[1]+c*256; f0 = g_pxL[0]+c*256; f1 = g_pxL[1]+c*256;
            ct = g_ctr + 92 + c; gs = 2;
        }
        run_unit<256>(Cm, sC, rb, f0, f1, h0, h1, ct, gs, LGA);
    }
}

// ---------------- final reduction to the scalar loss ------------------------
__global__ void k_combine(float* __restrict__ out) {
    __shared__ float red[4][4];
    int tid = threadIdx.x;                  // 256 threads
    float sfg_l = 0.f, spx_l = 0.f, sfg_g = 0.f, spx_g = 0.f;
    for (int i = tid; i < 14336; i += 256) sfg_l += g_fL[1][i] + g_gL[1][i];
    for (int i = tid; i < 4096;  i += 256) spx_l += g_pxL[1][i];
    for (int i = tid; i < 14336; i += 256) sfg_g += g_fG[1][i] + g_gG[1][i];
    for (int i = tid; i < 4096;  i += 256) spx_g += g_pxG[1][i];
    for (int o = 32; o; o >>= 1) {
        sfg_l += __shfl_xor(sfg_l, o); spx_l += __shfl_xor(spx_l, o);
        sfg_g += __shfl_xor(sfg_g, o); spx_g += __shfl_xor(spx_g, o);
    }
    int w = tid >> 6;
    if ((tid & 63) == 0) { red[0][w] = sfg_l; red[1][w] = spx_l; red[2][w] = sfg_g; red[3][w] = spx_g; }
    __syncthreads();
    if (tid == 0) {
        float SL = red[0][0]+red[0][1]+red[0][2]+red[0][3];
        float PL = red[1][0]+red[1][1]+red[1][2]+red[1][3];
        float SG = red[2][0]+red[2][1]+red[2][2]+red[2][3];
        float PG = red[3][0]+red[3][1]+red[3][2]+red[3][3];
        float local_l  = SL/14336.f - PL/2048.f;
        float global_l = SG/14336.f - PG/2048.f;
        out[0] = 1.0f*local_l + 0.5f*global_l;
    }
}

// ---------------- host launcher ---------------------------------------------
extern "C" void kernel_launch(void* const* d_in, const int* in_sizes, int n_in,
                              void* d_out, int out_size, void* d_ws, size_t ws_size,
                              hipStream_t stream) {
    (void)in_sizes; (void)n_in; (void)out_size; (void)d_ws; (void)ws_size;
    const float* feat  = (const float*)d_in[0];
    const int* labels  = (const int*)d_in[1];
    const int* subg    = (const int*)d_in[2];

    k_index  <<<24,    64, 0, stream>>>(labels, subg);
    k_gather <<<2048, 256, 0, stream>>>(feat);
    k_gemm   <<<6144, 256, 0, stream>>>();
    k_init   <<<256,  256, 0, stream>>>();
    k_sink   <<<768,  256, 0, stream>>>();
    k_combine<<<1,    256, 0, stream>>>((float*)d_out);
}

// Round 4
// 5081.916 us; speedup vs baseline: 1.5305x; 1.5305x over previous
//
#include <hip/hip_runtime.h>
#include <math.h>

#define LOG2E 1.4426950408889634f
#define LN2   0.6931471805599453f
#define LGA  -5.545177444479562f   // -ln 256
#define LGG  -6.238324625039508f   // -ln 512

typedef short    short8  __attribute__((ext_vector_type(8)));
typedef float    floatx4 __attribute__((ext_vector_type(4)));
typedef _Float16 half8   __attribute__((ext_vector_type(8)));

__constant__ int c_pi[28] = {0,0,0,0,0,0,0,1,1,1,1,1,1,2,2,2,2,2,3,3,3,3,4,4,4,5,5,6};
__constant__ int c_pj[28] = {1,2,3,4,5,6,7,2,3,4,5,6,7,3,4,5,6,7,4,5,6,7,5,6,7,6,7,7};

// ---------------- static device storage ----------------
__device__ unsigned short g_cellsL[16*256*256];   // bf16 bits, gathered local cells
__device__ unsigned short g_cellsG[8*512*256];    // bf16 bits, gathered global cells
__device__ float g_x2L[16*256];
__device__ float g_x2G[8*512];
__device__ int   g_idxL[16*256];
__device__ int   g_idxG[8*512];
// fp16 cost matrices. Local: [0,56)=Cxy, [56,112)=Cyx(T), [112,128)=Cxx. 16.8 MB
__device__ _Float16 g_CL[128*256*256];
// Global: [0,28)=Cxy, [28,56)=Cyx(T), [56,64)=Cxx. 33.6 MB
__device__ _Float16 g_CG[64*512*512];
__device__ float g_fL[2][56*256];
__device__ float g_gL[2][56*256];
__device__ float g_pxL[2][16*256];
__device__ float g_fG[2][28*512];
__device__ float g_gG[2][28*512];
__device__ float g_pxG[2][8*512];
__device__ unsigned g_ctr[108];                   // per-group barrier counters

// ---------------- helpers ----------------
__device__ __forceinline__ unsigned short f2bf(float f) {
    unsigned u = __float_as_uint(f);
    u += 0x7fffu + ((u >> 16) & 1u);          // RNE; inputs are finite
    return (unsigned short)(u >> 16);
}

// ---------------- index lists: first-m matches in order (ballot scan) -------
__global__ void k_index(const int* __restrict__ labels, const int* __restrict__ subg) {
    int b = blockIdx.x, lane = threadIdx.x;   // 24 blocks x 64 threads
    int want_l, want_s, cap; int* out;
    if (b < 16) { want_l = b >> 3; want_s = b & 7; cap = 256; out = g_idxL + b*256; }
    else        { want_l = -1;     want_s = b - 16; cap = 512; out = g_idxG + (b-16)*512; }
    int cnt = 0;
    for (int base = 0; base < 4096; base += 64) {
        int i = base + lane;
        bool m = (subg[i] == want_s) && (want_l < 0 || labels[i] == want_l);
        unsigned long long mask = __ballot(m);
        int pos = cnt + __popcll(mask & ((1ull << lane) - 1ull));
        if (m && pos < cap) out[pos] = i;
        cnt += __popcll(mask);
    }
}

// ---------------- gather rows -> bf16 cells + fp32 sq-norms -----------------
__global__ void k_gather(const float* __restrict__ feat) {
    int wv = blockIdx.x*4 + (threadIdx.x >> 6);   // 8192 waves, one row each
    int lane = threadIdx.x & 63;
    const float* src; unsigned short* dst; float* x2out;
    if (wv < 4096) {
        int c = wv >> 8, row = wv & 255;
        src = feat + (size_t)g_idxL[c*256+row]*256;
        dst = g_cellsL + (size_t)(c*256+row)*256;
        x2out = g_x2L + c*256 + row;
    } else {
        int v = wv - 4096; int c = v >> 9, row = v & 511;
        src = feat + (size_t)g_idxG[c*512+row]*256;
        dst = g_cellsG + (size_t)(c*512+row)*256;
        x2out = g_x2G + c*512 + row;
    }
    floatx4 v4 = *(const floatx4*)(src + lane*4);
    float s = v4[0]*v4[0] + v4[1]*v4[1] + v4[2]*v4[2] + v4[3]*v4[3];
    unsigned lo = (unsigned)f2bf(v4[0]) | ((unsigned)f2bf(v4[1]) << 16);
    unsigned hi = (unsigned)f2bf(v4[2]) | ((unsigned)f2bf(v4[3]) << 16);
    unsigned* d32 = (unsigned*)dst;
    d32[lane*2] = lo; d32[lane*2+1] = hi;
    for (int o = 32; o; o >>= 1) s += __shfl_xor(s, o);
    if (lane == 0) *x2out = s;
}

// ---------------- cost matrices via bf16 MFMA, 64x64 tile per block ---------
__global__ __launch_bounds__(256) void k_gemm() {
    __shared__ _Float16 sB[16384];            // 32 KB
    int b = blockIdx.x, tid = threadIdx.x, lane = tid & 63, w = tid >> 6;
    const unsigned short *A, *B; _Float16* Cout; const float *x2a, *x2b;
    int m, tI, tJ;
    if (b < 2048) {                            // local: 128 matrices x 16 tiles
        int mm = b >> 4, t = b & 15; tI = t >> 2; tJ = t & 3; m = 256;
        int ca, cb;
        if (mm < 56)       { int lbl = mm/28,  q = mm%28;  ca = lbl*8 + c_pi[q]; cb = lbl*8 + c_pj[q]; }
        else if (mm < 112) { int p = mm-56; int lbl = p/28, q = p%28;
                             ca = lbl*8 + c_pj[q]; cb = lbl*8 + c_pi[q]; }
        else               { int c = mm-112; ca = cb = c; }
        A = g_cellsL + (size_t)ca*65536; B = g_cellsL + (size_t)cb*65536;
        x2a = g_x2L + ca*256; x2b = g_x2L + cb*256;
        Cout = g_CL + (size_t)mm*65536;
    } else {                                   // global: 64 matrices x 64 tiles
        int v = b - 2048; int mm = v >> 6, t = v & 63; tI = t >> 3; tJ = t & 7; m = 512;
        int ca, cb;
        if (mm < 28)      { ca = c_pi[mm];    cb = c_pj[mm]; }
        else if (mm < 56) { ca = c_pj[mm-28]; cb = c_pi[mm-28]; }
        else              { ca = cb = mm-56; }
        A = g_cellsG + (size_t)ca*131072; B = g_cellsG + (size_t)cb*131072;
        x2a = g_x2G + ca*512; x2b = g_x2G + cb*512;
        Cout = g_CG + (size_t)mm*262144;
    }
    const unsigned short* Bp0 = B + (size_t)(tJ*64)*256;
    for (int i = tid; i < 2048; i += 256) {
        int j = i >> 5, c8 = i & 31, kk = c8 >> 2, q = c8 & 3;
        *(short8*)(sB + (size_t)((kk*64 + j)*4 + q)*8) = *(const short8*)(Bp0 + j*256 + c8*8);
    }
    int r = lane & 15, quad = lane >> 4;
    const unsigned short* Ap = A + (size_t)(tI*64 + w*16 + r)*256 + quad*8;
    short8 a[8];
    #pragma unroll
    for (int kk = 0; kk < 8; kk++) a[kk] = *(const short8*)(Ap + kk*32);
    __syncthreads();
    #pragma unroll
    for (int tj = 0; tj < 4; tj++) {
        floatx4 acc = {0.f, 0.f, 0.f, 0.f};
        #pragma unroll
        for (int kk = 0; kk < 8; kk++) {
            short8 bv = *(const short8*)(sB + (size_t)((kk*64 + tj*16 + r)*4 + quad)*8);
            acc = __builtin_amdgcn_mfma_f32_16x16x32_bf16(a[kk], bv, acc, 0, 0, 0);
        }
        int jc = tJ*64 + tj*16 + r;
        float y2 = x2b[jc];
        #pragma unroll
        for (int rr = 0; rr < 4; rr++) {
            int ir = tI*64 + w*16 + quad*4 + rr;
            float v = x2a[ir] + y2 - 2.f*acc[rr];
            Cout[(size_t)ir*m + jc] = (_Float16)(0.5f*fmaxf(v, 0.f));
        }
    }
}

// ---------------- zero parity-0 potentials + barrier counters ---------------
__global__ void k_init() {
    int t = blockIdx.x*256 + threadIdx.x;   // 65536 threads
    if (t < 108) g_ctr[t] = 0;
    if      (t < 14336) g_fL[0][t] = 0.f;
    else if (t < 28672) g_gL[0][t-14336] = 0.f;
    else if (t < 32768) g_pxL[0][t-28672] = 0.f;
    else if (t < 47104) g_fG[0][t-32768] = 0.f;
    else if (t < 61440) g_gG[0][t-47104] = 0.f;
    else                g_pxG[0][t-61440] = 0.f;
}

// ---------------- persistent Sinkhorn unit runner ---------------------------
// All cross-block exchange uses RELAXED agent-scope atomics: these bypass
// L1/L2 (sc-bit encoding) and complete at the Infinity-Cache coherence point.
// NO acquire/release — on gfx950 those emit buffer_inv / buffer_wbl2 (full
// per-XCD L2 invalidate/writeback), which was the round-3 disaster.
// Ordering: __syncthreads() drains vmcnt(0) (bypassing stores are mall-acked
// => globally visible) before the counter add; asm memory fences stop the
// compiler from hoisting h-loads above the spin.
template<int M>
__device__ void run_unit(const _Float16* __restrict__ Cmat, _Float16* sC,
                         int rb, float* fv0, float* fv1,
                         const float* hv0, const float* hv1,
                         unsigned* ctr, int gsize, float loga)
{
    const int LR = (M == 256) ? 80 : 40;    // rows resident in LDS (40 KB)
    const int W0 = (M == 256) ? 16 : 32;    // shfl butterfly start
    int tid = threadIdx.x, lane = tid & 63, w = tid >> 6;
    int co = (M == 256) ? (lane & 31) : lane;
    int rsel = (M == 256) ? (lane >> 5) : 0;

    // park rows [rb, rb+LR) in LDS (contiguous 40 KB copy)
    {
        const short8* src8 = (const short8*)(Cmat + (size_t)rb*M);
        short8* dst8 = (short8*)sC;
        for (int i = tid; i < 2560; i += 256) dst8[i] = src8[i];
    }
    __syncthreads();

    float fprev[16];
    #pragma unroll
    for (int s = 0; s < 16; s++) fprev[s] = 0.f;   // parity-0 carry = zeros

    double e = 1024.0;                      // eps schedule, ratio 0.81, clip 1e-8
    unsigned tgt = 0;
    for (int k = 0; k < 123; k++) {
        bool fin = (k == 122);              // final extrapolation pass
        double ed = (e < 1e-8) ? 1e-8 : e;
        e *= 0.81;
        float eps = (float)ed;
        float inv_eps = (float)(1.0/ed);
        int po = fin ? 0 : (k & 1);
        bool hard = (eps < 1e-5f);          // |err| <= eps*ln(M): negligible
        const float* hs = po ? hv1 : hv0;
        float* fn = po ? fv0 : fv1;

        float h[8];
        #pragma unroll
        for (int q = 0; q < 8; q++) {
            float hq = __hip_atomic_load((float*)&hs[co*8 + q],
                                         __ATOMIC_RELAXED, __HIP_MEMORY_SCOPE_AGENT);
            h[q] = loga + hq*inv_eps;
        }
        #pragma unroll
        for (int s = 0; s < 16; s++) {
            int row = (M == 256) ? (w*32 + s*2 + rsel) : (w*16 + s);
            half8 cv;
            if (row < LR) cv = *(const half8*)(sC + (size_t)row*M + co*8);
            else          cv = *(const half8*)(Cmat + (size_t)(rb + row)*M + co*8);
            float tv[8]; float mx = -3.4e38f;
            #pragma unroll
            for (int q = 0; q < 8; q++) {
                float t = fmaf(-(float)cv[q], inv_eps, h[q]);
                tv[q] = t; mx = fmaxf(mx, t);
            }
            #pragma unroll
            for (int o = W0; o; o >>= 1) mx = fmaxf(mx, __shfl_xor(mx, o));
            float ft;
            if (!hard) {
                float sum = 0.f;
                #pragma unroll
                for (int q = 0; q < 8; q++) sum += exp2f((tv[q] - mx)*LOG2E);
                #pragma unroll
                for (int o = W0; o; o >>= 1) sum += __shfl_xor(sum, o);
                ft = -eps*(mx + LN2*__log2f(sum));
            } else {
                ft = -eps*mx;
            }
            float fnew = fin ? ft : 0.5f*(fprev[s] + ft);
            fprev[s] = fnew;
            if (co == 0)
                __hip_atomic_store(&fn[rb + row], fnew,
                                   __ATOMIC_RELAXED, __HIP_MEMORY_SCOPE_AGENT);
        }
        if (!fin) {                         // group barrier (Jacobi exchange)
            tgt += (unsigned)gsize;
            asm volatile("" ::: "memory");
            __syncthreads();                // drains vmcnt(0): stores mall-visible
            if (tid == 0) {
                __hip_atomic_fetch_add(ctr, 1u, __ATOMIC_RELAXED, __HIP_MEMORY_SCOPE_AGENT);
                while (__hip_atomic_load(ctr, __ATOMIC_RELAXED, __HIP_MEMORY_SCOPE_AGENT) < tgt)
                    __builtin_amdgcn_s_sleep(2);
            }
            asm volatile("" ::: "memory");
            __syncthreads();
            asm volatile("" ::: "memory"); // no hoisting of next-iter h loads
        }
    }
}

// 768 blocks: [0,224) gpair-f | [224,448) gpair-g | [448,512) gcell |
//             [512,624) lpair-f | [624,736) lpair-g | [736,768) lcell
__global__ __launch_bounds__(256, 3) void k_sink() {
    __shared__ _Float16 sC[20480];          // 40 KB slab
    int b = blockIdx.x;
    if (b < 512) {                          // global units, M=512, 64 rows/block
        const _Float16* Cm; float *f0, *f1; const float *h0, *h1;
        unsigned* ct; int gs, rb;
        if (b < 448) {
            int side = (b >= 224); int v = side ? b - 224 : b;
            int p = v >> 3, j = v & 7; rb = j*64;
            Cm = g_CG + (size_t)(side ? 28 + p : p)*262144;
            if (!side) { h0 = g_gG[0]+p*512; h1 = g_gG[1]+p*512; f0 = g_fG[0]+p*512; f1 = g_fG[1]+p*512; }
            else       { h0 = g_fG[0]+p*512; h1 = g_fG[1]+p*512; f0 = g_gG[0]+p*512; f1 = g_gG[1]+p*512; }
            ct = g_ctr + p; gs = 16;
        } else {
            int v = b - 448; int c = v >> 3, j = v & 7; rb = j*64;
            Cm = g_CG + (size_t)(56 + c)*262144;
            h0 = g_pxG[0]+c*512; h1 = g_pxG[1]+c*512; f0 = g_pxG[0]+c*512; f1 = g_pxG[1]+c*512;
            ct = g_ctr + 28 + c; gs = 8;
        }
        run_unit<512>(Cm, sC, rb, f0, f1, h0, h1, ct, gs, LGG);
    } else {                                // local units, M=256, 128 rows/block
        const _Float16* Cm; float *f0, *f1; const float *h0, *h1;
        unsigned* ct; int gs, rb;
        int v = b - 512;
        if (v < 224) {
            int side = (v >= 112); int u = side ? v - 112 : v;
            int p = u >> 1, j = u & 1; rb = j*128;
            Cm = g_CL + (size_t)(side ? 56 + p : p)*65536;
            if (!side) { h0 = g_gL[0]+p*256; h1 = g_gL[1]+p*256; f0 = g_fL[0]+p*256; f1 = g_fL[1]+p*256; }
            else       { h0 = g_fL[0]+p*256; h1 = g_fL[1]+p*256; f0 = g_gL[0]+p*256; f1 = g_gL[1]+p*256; }
            ct = g_ctr + 36 + p; gs = 4;
        } else {
            int u = v - 224; int c = u >> 1, j = u & 1; rb = j*128;
            Cm = g_CL + (size_t)(112 + c)*65536;
            h0 = g_pxL[0]+c*256; h1 = g_pxL[1]+c*256; f0 = g_pxL[0]+c*256; f1 = g_pxL[1]+c*256;
            ct = g_ctr + 92 + c; gs = 2;
        }
        run_unit<256>(Cm, sC, rb, f0, f1, h0, h1, ct, gs, LGA);
    }
}

// ---------------- final reduction to the scalar loss ------------------------
__global__ void k_combine(float* __restrict__ out) {
    __shared__ float red[4][4];
    int tid = threadIdx.x;                  // 256 threads
    float sfg_l = 0.f, spx_l = 0.f, sfg_g = 0.f, spx_g = 0.f;
    for (int i = tid; i < 14336; i += 256) sfg_l += g_fL[1][i] + g_gL[1][i];
    for (int i = tid; i < 4096;  i += 256) spx_l += g_pxL[1][i];
    for (int i = tid; i < 14336; i += 256) sfg_g += g_fG[1][i] + g_gG[1][i];
    for (int i = tid; i < 4096;  i += 256) spx_g += g_pxG[1][i];
    for (int o = 32; o; o >>= 1) {
        sfg_l += __shfl_xor(sfg_l, o); spx_l += __shfl_xor(spx_l, o);
        sfg_g += __shfl_xor(sfg_g, o); spx_g += __shfl_xor(spx_g, o);
    }
    int w = tid >> 6;
    if ((tid & 63) == 0) { red[0][w] = sfg_l; red[1][w] = spx_l; red[2][w] = sfg_g; red[3][w] = spx_g; }
    __syncthreads();
    if (tid == 0) {
        float SL = red[0][0]+red[0][1]+red[0][2]+red[0][3];
        float PL = red[1][0]+red[1][1]+red[1][2]+red[1][3];
        float SG = red[2][0]+red[2][1]+red[2][2]+red[2][3];
        float PG = red[3][0]+red[3][1]+red[3][2]+red[3][3];
        float local_l  = SL/14336.f - PL/2048.f;
        float global_l = SG/14336.f - PG/2048.f;
        out[0] = 1.0f*local_l + 0.5f*global_l;
    }
}

// ---------------- host launcher ---------------------------------------------
extern "C" void kernel_launch(void* const* d_in, const int* in_sizes, int n_in,
                              void* d_out, int out_size, void* d_ws, size_t ws_size,
                              hipStream_t stream) {
    (void)in_sizes; (void)n_in; (void)out_size; (void)d_ws; (void)ws_size;
    const float* feat  = (const float*)d_in[0];
    const int* labels  = (const int*)d_in[1];
    const int* subg    = (const int*)d_in[2];

    k_index  <<<24,    64, 0, stream>>>(labels, subg);
    k_gather <<<2048, 256, 0, stream>>>(feat);
    k_gemm   <<<6144, 256, 0, stream>>>();
    k_init   <<<256,  256, 0, stream>>>();
    k_sink   <<<768,  256, 0, stream>>>();
    k_combine<<<1,    256, 0, stream>>>((float*)d_out);
}

// Round 5
// 2832.672 us; speedup vs baseline: 2.7458x; 1.7940x over previous
//
#include <hip/hip_runtime.h>
#include <math.h>

#define LOG2E 1.4426950408889634f
#define LN2   0.6931471805599453f
#define LGA  -5.545177444479562f   // -ln 256
#define LGG  -6.238324625039508f   // -ln 512

typedef short    short8  __attribute__((ext_vector_type(8)));
typedef float    floatx4 __attribute__((ext_vector_type(4)));
typedef _Float16 half8   __attribute__((ext_vector_type(8)));

__constant__ int c_pi[28] = {0,0,0,0,0,0,0,1,1,1,1,1,1,2,2,2,2,2,3,3,3,3,4,4,4,5,5,6};
__constant__ int c_pj[28] = {1,2,3,4,5,6,7,2,3,4,5,6,7,3,4,5,6,7,4,5,6,7,5,6,7,6,7,7};

// ---------------- static device storage ----------------
__device__ unsigned short g_cellsL[16*256*256];   // bf16 bits, gathered local cells
__device__ unsigned short g_cellsG[8*512*256];    // bf16 bits, gathered global cells
__device__ float g_x2L[16*256];
__device__ float g_x2G[8*512];
__device__ int   g_idxL[16*256];
__device__ int   g_idxG[8*512];
// fp16 cost matrices. Local: [0,56)=Cxy, [56,112)=Cyx(T), [112,128)=Cxx. 16.8 MB
__device__ _Float16 g_CL[128*256*256];
// Global: [0,28)=Cxy, [28,56)=Cyx(T), [56,64)=Cxx. 33.6 MB
__device__ _Float16 g_CG[64*512*512];
__device__ float g_fL[2][56*256];
__device__ float g_gL[2][56*256];
__device__ float g_pxL[2][16*256];
__device__ float g_fG[2][28*512];
__device__ float g_gG[2][28*512];
__device__ float g_pxG[2][8*512];
__device__ unsigned g_ctr[108];                   // per-group barrier counters

// ---------------- helpers ----------------
__device__ __forceinline__ unsigned short f2bf(float f) {
    unsigned u = __float_as_uint(f);
    u += 0x7fffu + ((u >> 16) & 1u);          // RNE; inputs are finite
    return (unsigned short)(u >> 16);
}

// ---------------- index lists: first-m matches in order (ballot scan) -------
__global__ void k_index(const int* __restrict__ labels, const int* __restrict__ subg) {
    int b = blockIdx.x, lane = threadIdx.x;   // 24 blocks x 64 threads
    int want_l, want_s, cap; int* out;
    if (b < 16) { want_l = b >> 3; want_s = b & 7; cap = 256; out = g_idxL + b*256; }
    else        { want_l = -1;     want_s = b - 16; cap = 512; out = g_idxG + (b-16)*512; }
    int cnt = 0;
    for (int base = 0; base < 4096; base += 64) {
        int i = base + lane;
        bool m = (subg[i] == want_s) && (want_l < 0 || labels[i] == want_l);
        unsigned long long mask = __ballot(m);
        int pos = cnt + __popcll(mask & ((1ull << lane) - 1ull));
        if (m && pos < cap) out[pos] = i;
        cnt += __popcll(mask);
    }
}

// ---------------- gather rows -> bf16 cells + fp32 sq-norms -----------------
__global__ void k_gather(const float* __restrict__ feat) {
    int wv = blockIdx.x*4 + (threadIdx.x >> 6);   // 8192 waves, one row each
    int lane = threadIdx.x & 63;
    const float* src; unsigned short* dst; float* x2out;
    if (wv < 4096) {
        int c = wv >> 8, row = wv & 255;
        src = feat + (size_t)g_idxL[c*256+row]*256;
        dst = g_cellsL + (size_t)(c*256+row)*256;
        x2out = g_x2L + c*256 + row;
    } else {
        int v = wv - 4096; int c = v >> 9, row = v & 511;
        src = feat + (size_t)g_idxG[c*512+row]*256;
        dst = g_cellsG + (size_t)(c*512+row)*256;
        x2out = g_x2G + c*512 + row;
    }
    floatx4 v4 = *(const floatx4*)(src + lane*4);
    float s = v4[0]*v4[0] + v4[1]*v4[1] + v4[2]*v4[2] + v4[3]*v4[3];
    unsigned lo = (unsigned)f2bf(v4[0]) | ((unsigned)f2bf(v4[1]) << 16);
    unsigned hi = (unsigned)f2bf(v4[2]) | ((unsigned)f2bf(v4[3]) << 16);
    unsigned* d32 = (unsigned*)dst;
    d32[lane*2] = lo; d32[lane*2+1] = hi;
    for (int o = 32; o; o >>= 1) s += __shfl_xor(s, o);
    if (lane == 0) *x2out = s;
}

// ---------------- cost matrices via bf16 MFMA, 64x64 tile per block ---------
__global__ __launch_bounds__(256) void k_gemm() {
    __shared__ _Float16 sB[16384];            // 32 KB
    int b = blockIdx.x, tid = threadIdx.x, lane = tid & 63, w = tid >> 6;
    const unsigned short *A, *B; _Float16* Cout; const float *x2a, *x2b;
    int m, tI, tJ;
    if (b < 2048) {                            // local: 128 matrices x 16 tiles
        int mm = b >> 4, t = b & 15; tI = t >> 2; tJ = t & 3; m = 256;
        int ca, cb;
        if (mm < 56)       { int lbl = mm/28,  q = mm%28;  ca = lbl*8 + c_pi[q]; cb = lbl*8 + c_pj[q]; }
        else if (mm < 112) { int p = mm-56; int lbl = p/28, q = p%28;
                             ca = lbl*8 + c_pj[q]; cb = lbl*8 + c_pi[q]; }
        else               { int c = mm-112; ca = cb = c; }
        A = g_cellsL + (size_t)ca*65536; B = g_cellsL + (size_t)cb*65536;
        x2a = g_x2L + ca*256; x2b = g_x2L + cb*256;
        Cout = g_CL + (size_t)mm*65536;
    } else {                                   // global: 64 matrices x 64 tiles
        int v = b - 2048; int mm = v >> 6, t = v & 63; tI = t >> 3; tJ = t & 7; m = 512;
        int ca, cb;
        if (mm < 28)      { ca = c_pi[mm];    cb = c_pj[mm]; }
        else if (mm < 56) { ca = c_pj[mm-28]; cb = c_pi[mm-28]; }
        else              { ca = cb = mm-56; }
        A = g_cellsG + (size_t)ca*131072; B = g_cellsG + (size_t)cb*131072;
        x2a = g_x2G + ca*512; x2b = g_x2G + cb*512;
        Cout = g_CG + (size_t)mm*262144;
    }
    const unsigned short* Bp0 = B + (size_t)(tJ*64)*256;
    for (int i = tid; i < 2048; i += 256) {
        int j = i >> 5, c8 = i & 31, kk = c8 >> 2, q = c8 & 3;
        *(short8*)(sB + (size_t)((kk*64 + j)*4 + q)*8) = *(const short8*)(Bp0 + j*256 + c8*8);
    }
    int r = lane & 15, quad = lane >> 4;
    const unsigned short* Ap = A + (size_t)(tI*64 + w*16 + r)*256 + quad*8;
    short8 a[8];
    #pragma unroll
    for (int kk = 0; kk < 8; kk++) a[kk] = *(const short8*)(Ap + kk*32);
    __syncthreads();
    #pragma unroll
    for (int tj = 0; tj < 4; tj++) {
        floatx4 acc = {0.f, 0.f, 0.f, 0.f};
        #pragma unroll
        for (int kk = 0; kk < 8; kk++) {
            short8 bv = *(const short8*)(sB + (size_t)((kk*64 + tj*16 + r)*4 + quad)*8);
            acc = __builtin_amdgcn_mfma_f32_16x16x32_bf16(a[kk], bv, acc, 0, 0, 0);
        }
        int jc = tJ*64 + tj*16 + r;
        float y2 = x2b[jc];
        #pragma unroll
        for (int rr = 0; rr < 4; rr++) {
            int ir = tI*64 + w*16 + quad*4 + rr;
            float v = x2a[ir] + y2 - 2.f*acc[rr];
            Cout[(size_t)ir*m + jc] = (_Float16)(0.5f*fmaxf(v, 0.f));
        }
    }
}

// ---------------- zero parity-0 potentials + barrier counters ---------------
__global__ void k_init() {
    int t = blockIdx.x*256 + threadIdx.x;   // 65536 threads
    if (t < 108) g_ctr[t] = 0;
    if      (t < 14336) g_fL[0][t] = 0.f;
    else if (t < 28672) g_gL[0][t-14336] = 0.f;
    else if (t < 32768) g_pxL[0][t-28672] = 0.f;
    else if (t < 47104) g_fG[0][t-32768] = 0.f;
    else if (t < 61440) g_gG[0][t-47104] = 0.f;
    else                g_pxG[0][t-61440] = 0.f;
}

// one softmin row: cv = 8 fp16 C entries, IDX = carry slot, ROW = sF slot
#define PROC(cvv, IDX, ROW)                                              \
    {                                                                    \
        float tv[8]; float mx = -3.4e38f;                                \
        _Pragma("unroll")                                                \
        for (int q = 0; q < 8; q++) {                                    \
            float t = fmaf(-(float)(cvv)[q], inv_eps, h[q]);             \
            tv[q] = t; mx = fmaxf(mx, t);                                \
        }                                                                \
        _Pragma("unroll")                                                \
        for (int o = W0; o; o >>= 1) mx = fmaxf(mx, __shfl_xor(mx, o));  \
        float ft;                                                        \
        if (!hard) {                                                     \
            float sum = 0.f;                                             \
            _Pragma("unroll")                                            \
            for (int q = 0; q < 8; q++) sum += exp2f((tv[q]-mx)*LOG2E);  \
            _Pragma("unroll")                                            \
            for (int o = W0; o; o >>= 1) sum += __shfl_xor(sum, o);      \
            ft = -eps*(mx + LN2*__log2f(sum));                           \
        } else ft = -eps*mx;                                             \
        float fnew = fin ? ft : 0.5f*(fprev[IDX] + ft);                  \
        fprev[IDX] = fnew;                                               \
        if (wr) sF[ROW] = fnew;                                          \
    }

// ---------------- persistent Sinkhorn unit runner ---------------------------
// Exchange via RELAXED agent-scope atomics ONLY (no acquire/release: those
// emit buffer_inv/buffer_wbl2 = r3 disaster). r4 lesson: bypass traffic must
// be COALESCED — scattered single-dword bypass stores caused ~196 MB of
// sector-RMW write amplification. Here: h staged to LDS via sector-complete
// coalesced loads; f assembled in LDS, written as one coalesced store.
template<int M>
__device__ void run_unit(const _Float16* __restrict__ Cmat, _Float16* sC,
                         float* sH, float* sF,
                         int rb, float* fv0, float* fv1,
                         const float* hv0, const float* hv1,
                         unsigned* ctr, int gsize, float loga)
{
    const int LR    = (M == 256) ? 80 : 40;   // LDS-parked rows (40 KB)
    const int NL    = 10, NG = 6;             // s-steps: LDS rows / streamed rows
    const int W0    = (M == 256) ? 16 : 32;   // shfl butterfly start
    const int RSTEP = (M == 256) ? 8 : 4;     // row stride between s-steps
    const int NR    = (M == 256) ? 128 : 64;  // rows per block
    int tid = threadIdx.x, lane = tid & 63, w = tid >> 6;
    int co   = (M == 256) ? (lane & 31) : lane;
    int wofs = (M == 256) ? (w*2 + (lane >> 5)) : w;   // row offset of this (half)wave
    bool wr  = (co == 0);

    // park rows [rb, rb+LR) in LDS (contiguous 40 KB copy)
    {
        const short8* src8 = (const short8*)(Cmat + (size_t)rb*M);
        short8* dst8 = (short8*)sC;
        for (int i = tid; i < LR*M/8; i += 256) dst8[i] = src8[i];
    }

    float fprev[16];
    #pragma unroll
    for (int s = 0; s < 16; s++) fprev[s] = 0.f;   // parity-0 carry = zeros

    const _Float16* gbase = Cmat + (size_t)(rb + NL*RSTEP + wofs)*M + co*8;

    double e = 1024.0;                      // eps schedule, ratio 0.81, clip 1e-8
    unsigned tgt = 0;
    for (int k = 0; k < 123; k++) {
        bool fin = (k == 122);              // final extrapolation pass
        double ed = (e < 1e-8) ? 1e-8 : e;
        e *= 0.81;
        float eps = (float)ed;
        float inv_eps = (float)(1.0/ed);
        int po = fin ? 0 : (k & 1);
        bool hard = (eps < 1e-5f);          // |err| <= eps*ln(M): negligible
        const float* hs = po ? hv1 : hv0;
        float* fn = po ? fv0 : fv1;

        // stage h -> LDS with fully-coalesced bypass loads (sector-complete)
        sH[tid] = __hip_atomic_load((float*)&hs[tid], __ATOMIC_RELAXED,
                                    __HIP_MEMORY_SCOPE_AGENT);
        if (M == 512)
            sH[256 + tid] = __hip_atomic_load((float*)&hs[256 + tid],
                                 __ATOMIC_RELAXED, __HIP_MEMORY_SCOPE_AGENT);
        __syncthreads();

        float h[8];
        {
            floatx4 h0 = *(const floatx4*)(sH + co*8);
            floatx4 h1 = *(const floatx4*)(sH + co*8 + 4);
            #pragma unroll
            for (int q = 0; q < 4; q++) {
                h[q]   = fmaf(h0[q], inv_eps, loga);
                h[4+q] = fmaf(h1[q], inv_eps, loga);
            }
        }

        // issue all streamed-row loads up front (hide L2 latency under LDS rows)
        half8 gbuf[NG];
        #pragma unroll
        for (int sg = 0; sg < NG; sg++)
            gbuf[sg] = *(const half8*)(gbase + (size_t)sg*RSTEP*M);

        // LDS-resident rows
        #pragma unroll
        for (int s = 0; s < NL; s++) {
            int row = s*RSTEP + wofs;
            half8 cv = *(const half8*)(sC + (size_t)row*M + co*8);
            PROC(cv, s, row)
        }
        // streamed rows
        #pragma unroll
        for (int sg = 0; sg < NG; sg++) {
            int row = (NL+sg)*RSTEP + wofs;
            PROC(gbuf[sg], NL+sg, row)
        }

        __syncthreads();                    // sF complete
        if (tid < NR)                       // one coalesced bypass store
            __hip_atomic_store(&fn[rb + tid], sF[tid],
                               __ATOMIC_RELAXED, __HIP_MEMORY_SCOPE_AGENT);
        if (!fin) {                         // group barrier (Jacobi exchange)
            tgt += (unsigned)gsize;
            asm volatile("" ::: "memory");
            __syncthreads();                // drains vmcnt: stores mall-visible
            if (tid == 0) {
                __hip_atomic_fetch_add(ctr, 1u, __ATOMIC_RELAXED, __HIP_MEMORY_SCOPE_AGENT);
                while (__hip_atomic_load(ctr, __ATOMIC_RELAXED, __HIP_MEMORY_SCOPE_AGENT) < tgt)
                    __builtin_amdgcn_s_sleep(2);
            }
            asm volatile("" ::: "memory");
            __syncthreads();
            asm volatile("" ::: "memory");
        }
    }
}

// 768 blocks: [0,224) gpair-f | [224,448) gpair-g | [448,512) gcell |
//             [512,624) lpair-f | [624,736) lpair-g | [736,768) lcell
__global__ __launch_bounds__(256, 3) void k_sink() {
    __shared__ _Float16 sC[20480];          // 40 KB slab
    __shared__ float sH[512];
    __shared__ float sF[128];
    int b = blockIdx.x;
    if (b < 512) {                          // global units, M=512, 64 rows/block
        const _Float16* Cm; float *f0, *f1; const float *h0, *h1;
        unsigned* ct; int gs, rb;
        if (b < 448) {
            int side = (b >= 224); int v = side ? b - 224 : b;
            int p = v >> 3, j = v & 7; rb = j*64;
            Cm = g_CG + (size_t)(side ? 28 + p : p)*262144;
            if (!side) { h0 = g_gG[0]+p*512; h1 = g_gG[1]+p*512; f0 = g_fG[0]+p*512; f1 = g_fG[1]+p*512; }
            else       { h0 = g_fG[0]+p*512; h1 = g_fG[1]+p*512; f0 = g_gG[0]+p*512; f1 = g_gG[1]+p*512; }
            ct = g_ctr + p; gs = 16;
        } else {
            int v = b - 448; int c = v >> 3, j = v & 7; rb = j*64;
            Cm = g_CG + (size_t)(56 + c)*262144;
            h0 = g_pxG[0]+c*512; h1 = g_pxG[1]+c*512; f0 = g_pxG[0]+c*512; f1 = g_pxG[1]+c*512;
            ct = g_ctr + 28 + c; gs = 8;
        }
        run_unit<512>(Cm, sC, sH, sF, rb, f0, f1, h0, h1, ct, gs, LGG);
    } else {                                // local units, M=256, 128 rows/block
        const _Float16* Cm; float *f0, *f1; const float *h0, *h1;
        unsigned* ct; int gs, rb;
        int v = b - 512;
        if (v < 224) {
            int side = (v >= 112); int u = side ? v - 112 : v;
            int p = u >> 1, j = u & 1; rb = j*128;
            Cm = g_CL + (size_t)(side ? 56 + p : p)*65536;
            if (!side) { h0 = g_gL[0]+p*256; h1 = g_gL[1]+p*256; f0 = g_fL[0]+p*256; f1 = g_fL[1]+p*256; }
            else       { h0 = g_fL[0]+p*256; h1 = g_fL[1]+p*256; f0 = g_gL[0]+p*256; f1 = g_gL[1]+p*256; }
            ct = g_ctr + 36 + p; gs = 4;
        } else {
            int u = v - 224; int c = u >> 1, j = u & 1; rb = j*128;
            Cm = g_CL + (size_t)(112 + c)*65536;
            h0 = g_pxL[0]+c*256; h1 = g_pxL[1]+c*256; f0 = g_pxL[0]+c*256; f1 = g_pxL[1]+c*256;
            ct = g_ctr + 92 + c; gs = 2;
        }
        run_unit<256>(Cm, sC, sH, sF, rb, f0, f1, h0, h1, ct, gs, LGA);
    }
}

// ---------------- final reduction to the scalar loss ------------------------
__global__ void k_combine(float* __restrict__ out) {
    __shared__ float red[4][4];
    int tid = threadIdx.x;                  // 256 threads
    float sfg_l = 0.f, spx_l = 0.f, sfg_g = 0.f, spx_g = 0.f;
    for (int i = tid; i < 14336; i += 256) sfg_l += g_fL[1][i] + g_gL[1][i];
    for (int i = tid; i < 4096;  i += 256) spx_l += g_pxL[1][i];
    for (int i = tid; i < 14336; i += 256) sfg_g += g_fG[1][i] + g_gG[1][i];
    for (int i = tid; i < 4096;  i += 256) spx_g += g_pxG[1][i];
    for (int o = 32; o; o >>= 1) {
        sfg_l += __shfl_xor(sfg_l, o); spx_l += __shfl_xor(spx_l, o);
        sfg_g += __shfl_xor(sfg_g, o); spx_g += __shfl_xor(spx_g, o);
    }
    int w = tid >> 6;
    if ((tid & 63) == 0) { red[0][w] = sfg_l; red[1][w] = spx_l; red[2][w] = sfg_g; red[3][w] = spx_g; }
    __syncthreads();
    if (tid == 0) {
        float SL = red[0][0]+red[0][1]+red[0][2]+red[0][3];
        float PL = red[1][0]+red[1][1]+red[1][2]+red[1][3];
        float SG = red[2][0]+red[2][1]+red[2][2]+red[2][3];
        float PG = red[3][0]+red[3][1]+red[3][2]+red[3][3];
        float local_l  = SL/14336.f - PL/2048.f;
        float global_l = SG/14336.f - PG/2048.f;
        out[0] = 1.0f*local_l + 0.5f*global_l;
    }
}

// ---------------- host launcher ---------------------------------------------
extern "C" void kernel_launch(void* const* d_in, const int* in_sizes, int n_in,
                              void* d_out, int out_size, void* d_ws, size_t ws_size,
                              hipStream_t stream) {
    (void)in_sizes; (void)n_in; (void)out_size; (void)d_ws; (void)ws_size;
    const float* feat  = (const float*)d_in[0];
    const int* labels  = (const int*)d_in[1];
    const int* subg    = (const int*)d_in[2];

    k_index  <<<24,    64, 0, stream>>>(labels, subg);
    k_gather <<<2048, 256, 0, stream>>>(feat);
    k_gemm   <<<6144, 256, 0, stream>>>();
    k_init   <<<256,  256, 0, stream>>>();
    k_sink   <<<768,  256, 0, stream>>>();
    k_combine<<<1,    256, 0, stream>>>((float*)d_out);
}